// Round 3
// baseline (1836.830 us; speedup 1.0000x reference)
//
#include <hip/hip_runtime.h>
#include <hip/hip_bf16.h>

// CrossNATBlock2D: B=1, H=W=128, C=128, HEADS=4, HD=32, K=7
// All inputs/outputs fp32 (per reference). q,v,k intermediates bf16 in d_ws
// (12 MB). x1 staged fp32 in d_out and overwritten in place by k_mlp.

#define N_PIX 16384
#define C 128
#define HEADS 4
#define HD 32
#define HW 128

typedef __hip_bfloat16 bf16;

__device__ __forceinline__ float b2f(bf16 v) { return __bfloat162float(v); }

__device__ __forceinline__ float wave_sum(float v) {
    for (int m = 1; m < 64; m <<= 1) v += __shfl_xor(v, m, 64);
    return v;
}
__device__ __forceinline__ float wave_max(float v) {
    for (int m = 1; m < 64; m <<= 1) v = fmaxf(v, __shfl_xor(v, m, 64));
    return v;
}

// ---------- kernel 1: LN1 + QV GEMM + K projection (one block per pixel) ----------
__global__ __launch_bounds__(256) void k_qkv(
    const float* __restrict__ x, const float* __restrict__ y,
    const float* __restrict__ qv_w, const float* __restrict__ qv_b,
    const float* __restrict__ k_w, const float* __restrict__ k_b,
    const float* __restrict__ n1_w, const float* __restrict__ n1_b,
    bf16* __restrict__ qb, bf16* __restrict__ vb, bf16* __restrict__ kb) {
    __shared__ float xr[C];
    __shared__ float xn[C];
    __shared__ float yr[C];
    __shared__ float s_mu, s_ri;
    const int pix = blockIdx.x;
    const int t = threadIdx.x;
    if (t < C) xr[t] = x[pix * C + t];
    else       yr[t - C] = y[pix * C + (t - C)];
    __syncthreads();
    if (t < 64) {
        float a = xr[t], b = xr[t + 64];
        float s = wave_sum(a + b);
        float sq = wave_sum(a * a + b * b);
        if (t == 0) {
            float mu = s * (1.0f / C);
            float var = sq * (1.0f / C) - mu * mu;
            s_mu = mu;
            s_ri = rsqrtf(var + 1e-5f);
        }
    }
    __syncthreads();
    if (t < C) xn[t] = (xr[t] - s_mu) * s_ri * n1_w[t] + n1_b[t];
    __syncthreads();
    const float scale = 0.1767766952966369f;  // 1/sqrt(32)
#pragma unroll
    for (int oo = 0; oo < 2; oo++) {
        const int o = t + oo * 256;
        if (o >= 384) break;
        float acc = 0.f;
        if (o < 256) {  // q or v: dot(xn, qv_w row o)
            const float* wrow = qv_w + o * C;
#pragma unroll 8
            for (int c = 0; c < C; c++) acc += xn[c] * wrow[c];
            acc += qv_b[o];
            if (o < C) qb[pix * C + o] = __float2bfloat16(acc * scale);
            else       vb[pix * C + (o - C)] = __float2bfloat16(acc);
        } else {        // k: dot(yr, k_w row o-256)
            const int ok = o - 256;
            const float* wrow = k_w + ok * C;
#pragma unroll 8
            for (int c = 0; c < C; c++) acc += yr[c] * wrow[c];
            acc += k_b[ok];
            kb[pix * C + ok] = __float2bfloat16(acc);
        }
    }
}

// ---------- kernel 2: NATTEN 7x7 attention + proj + residual (one block per pixel) ----------
// writes x1 = x + proj(attn_out) as fp32 into x1out (aliases d_out)
__global__ __launch_bounds__(256) void k_attn_proj(
    const bf16* __restrict__ qb, const bf16* __restrict__ kb,
    const bf16* __restrict__ vb, const float* __restrict__ rpb,
    const float* __restrict__ proj_w, const float* __restrict__ proj_b,
    const float* __restrict__ x, float* __restrict__ x1out) {
    __shared__ float sq[HEADS][HD];
    __shared__ float sp[HEADS][64];
    __shared__ float aoL[C];
    const int pix = blockIdx.x;
    const int t = threadIdx.x;
    const int h = t >> 6;
    const int lane = t & 63;
    const int i = pix >> 7, j = pix & 127;
    int sh = i - 3; sh = sh < 0 ? 0 : (sh > HW - 7 ? HW - 7 : sh);
    int sw = j - 3; sw = sw < 0 ? 0 : (sw > HW - 7 ? HW - 7 : sw);
    if (lane < HD) sq[h][lane] = b2f(qb[pix * C + h * HD + lane]);
    __syncthreads();
    float logit = -1e30f;
    if (lane < 49) {
        const int a = lane / 7, c2 = lane % 7;
        const int ni = sh + a, nj = sw + c2;
        const bf16* kp = kb + (ni * HW + nj) * C + h * HD;
        float acc = 0.f;
#pragma unroll
        for (int d = 0; d < HD; d++) acc += sq[h][d] * b2f(kp[d]);
        acc += rpb[h * 169 + (ni - i + 6) * 13 + (nj - j + 6)];
        logit = acc;
    }
    const float mx = wave_max(logit);
    const float e = (lane < 49) ? __expf(logit - mx) : 0.f;
    const float s = wave_sum(e);
    sp[h][lane] = e / s;
    __syncthreads();
    if (lane < HD) {
        float acc = 0.f;
#pragma unroll
        for (int a = 0; a < 49; a++) {
            const int ni = sh + a / 7, nj = sw + a % 7;
            acc += sp[h][a] * b2f(vb[(ni * HW + nj) * C + h * HD + lane]);
        }
        aoL[h * HD + lane] = acc;
    }
    __syncthreads();
    if (t < C) {
        const float* wrow = proj_w + t * C;
        float acc = 0.f;
#pragma unroll 8
        for (int c = 0; c < C; c++) acc += aoL[c] * wrow[c];
        acc += proj_b[t] + x[pix * C + t];
        x1out[pix * C + t] = acc;
    }
}

// ---------- kernel 3: LN2 + FC1 + GELU + FC2 + residual (one block per pixel) ----------
// reads x1 from io (d_out fp32), overwrites io in place with final output
__global__ __launch_bounds__(256) void k_mlp(
    float* __restrict__ io, const float* __restrict__ n2_w,
    const float* __restrict__ n2_b, const float* __restrict__ fc1_w,
    const float* __restrict__ fc1_b, const float* __restrict__ fc2_w,
    const float* __restrict__ fc2_b) {
    __shared__ float xr[C];
    __shared__ float xn[C];
    __shared__ float hbuf[512];
    __shared__ float s_mu, s_ri;
    const int pix = blockIdx.x;
    const int t = threadIdx.x;
    if (t < C) xr[t] = io[pix * C + t];
    __syncthreads();
    if (t < 64) {
        float a = xr[t], b = xr[t + 64];
        float s = wave_sum(a + b);
        float sq = wave_sum(a * a + b * b);
        if (t == 0) {
            float mu = s * (1.0f / C);
            float var = sq * (1.0f / C) - mu * mu;
            s_mu = mu;
            s_ri = rsqrtf(var + 1e-5f);
        }
    }
    __syncthreads();
    if (t < C) xn[t] = (xr[t] - s_mu) * s_ri * n2_w[t] + n2_b[t];
    __syncthreads();
#pragma unroll
    for (int oo = 0; oo < 2; oo++) {
        const int o = t + oo * 256;
        const float* wrow = fc1_w + o * C;
        float acc = 0.f;
#pragma unroll 8
        for (int c = 0; c < C; c++) acc += xn[c] * wrow[c];
        acc += fc1_b[o];
        hbuf[o] = 0.5f * acc * (1.f + erff(acc * 0.70710678118654752f));
    }
    __syncthreads();
    if (t < C) {
        const float* wrow = fc2_w + t * 512;
        float acc = 0.f;
#pragma unroll 8
        for (int c = 0; c < 512; c++) acc += hbuf[c] * wrow[c];
        acc += fc2_b[t] + xr[t];
        io[pix * C + t] = acc;
    }
}

extern "C" void kernel_launch(void* const* d_in, const int* in_sizes, int n_in,
                              void* d_out, int out_size, void* d_ws, size_t ws_size,
                              hipStream_t stream) {
    const float* x      = (const float*)d_in[0];
    const float* y      = (const float*)d_in[1];
    const float* qv_w   = (const float*)d_in[2];
    const float* qv_b   = (const float*)d_in[3];
    const float* k_w    = (const float*)d_in[4];
    const float* k_b    = (const float*)d_in[5];
    const float* rpb    = (const float*)d_in[6];
    const float* proj_w = (const float*)d_in[7];
    const float* proj_b = (const float*)d_in[8];
    const float* n1_w   = (const float*)d_in[9];
    const float* n1_b   = (const float*)d_in[10];
    const float* n2_w   = (const float*)d_in[11];
    const float* n2_b   = (const float*)d_in[12];
    const float* fc1_w  = (const float*)d_in[13];
    const float* fc1_b  = (const float*)d_in[14];
    const float* fc2_w  = (const float*)d_in[15];
    const float* fc2_b  = (const float*)d_in[16];
    float* out = (float*)d_out;

    bf16* qb = (bf16*)d_ws;                         // 16384*128 bf16 = 4 MB
    bf16* vb = qb + (size_t)N_PIX * C;              // 4 MB
    bf16* kb = vb + (size_t)N_PIX * C;              // 4 MB   (total 12 MB)

    k_qkv<<<N_PIX, 256, 0, stream>>>(x, y, qv_w, qv_b, k_w, k_b, n1_w, n1_b, qb, vb, kb);
    k_attn_proj<<<N_PIX, 256, 0, stream>>>(qb, kb, vb, rpb, proj_w, proj_b, x, out);
    k_mlp<<<N_PIX, 256, 0, stream>>>(out, n2_w, n2_b, fc1_w, fc1_b, fc2_w, fc2_b);
}

// Round 4
// 326.679 us; speedup vs baseline: 5.6227x; 5.6227x over previous
//
#include <hip/hip_runtime.h>
#include <hip/hip_bf16.h>

// CrossNATBlock2D: B=1, H=W=128, C=128, HEADS=4, HD=32, K=7  (fp32 I/O)
// R4: MFMA-based k_qkv and k_mlp (bf16 weights staged in ws). Attention kernel
// unchanged from R3 (passed; next target).
// ws layout (elems): qb[2M] vb[2M] kb[2M] bf16 (12 MB) + bf16 weights (352 KB).

#define N_PIX 16384
#define C 128
#define HEADS 4
#define HD 32
#define HW 128

typedef __hip_bfloat16 bf16;
typedef __attribute__((ext_vector_type(8))) short bf16x8;
typedef __attribute__((ext_vector_type(4))) float f32x4;

__device__ __forceinline__ float b2f(bf16 v) { return __bfloat162float(v); }
__device__ __forceinline__ short f2bs(float f) {
    bf16 h = __float2bfloat16(f);
    return (short)__bfloat16_as_ushort(h);
}

__device__ __forceinline__ float wave_sum(float v) {
    for (int m = 1; m < 64; m <<= 1) v += __shfl_xor(v, m, 64);
    return v;
}
__device__ __forceinline__ float wave_max(float v) {
    for (int m = 1; m < 64; m <<= 1) v = fmaxf(v, __shfl_xor(v, m, 64));
    return v;
}

// ---------- kernel 0: convert weights fp32 -> bf16 into ws ----------
__global__ __launch_bounds__(256) void k_wconv(
    const float* __restrict__ qv_w, const float* __restrict__ k_w,
    const float* __restrict__ fc1_w, const float* __restrict__ fc2_w,
    short* __restrict__ wqv, short* __restrict__ wk,
    short* __restrict__ wfc1, short* __restrict__ wfc2) {
    const int i = blockIdx.x * 256 + threadIdx.x;
    if (i < 32768) wqv[i] = f2bs(qv_w[i]);
    if (i < 16384) wk[i] = f2bs(k_w[i]);
    if (i < 65536) { wfc1[i] = f2bs(fc1_w[i]); wfc2[i] = f2bs(fc2_w[i]); }
}

// ---------- kernel 1: LN1 + QV GEMM + K proj, MFMA, 32 pixels/block ----------
__global__ __launch_bounds__(256) void k_qkv(
    const float* __restrict__ x, const float* __restrict__ y,
    const short* __restrict__ wqv, const float* __restrict__ qv_b,
    const short* __restrict__ wk, const float* __restrict__ k_b,
    const float* __restrict__ n1_w, const float* __restrict__ n1_b,
    bf16* __restrict__ qb, bf16* __restrict__ vb, bf16* __restrict__ kb) {
    __shared__ float xr[32][132];
    __shared__ short xn[32][136];   // +8 pad: row stride 68 dwords -> bank spread
    __shared__ short yb[32][136];
    __shared__ float redS[32][8], redQ[32][8];
    __shared__ float muA[32], riA[32];
    const int t = threadIdx.x;
    const int pix0 = blockIdx.x * 32;
    for (int e = t; e < 32 * 128; e += 256) {
        const int r = e >> 7, c = e & 127;
        xr[r][c] = x[(pix0 + r) * C + c];
        yb[r][c] = f2bs(y[(pix0 + r) * C + c]);
    }
    __syncthreads();
    {
        const int r = t >> 3, s = t & 7;
        float sm = 0.f, sq = 0.f;
        for (int i = 0; i < 16; i++) { float v = xr[r][s * 16 + i]; sm += v; sq += v * v; }
        redS[r][s] = sm; redQ[r][s] = sq;
    }
    __syncthreads();
    if (t < 32) {
        float sm = 0.f, sq = 0.f;
        for (int s = 0; s < 8; s++) { sm += redS[t][s]; sq += redQ[t][s]; }
        const float mu = sm * (1.f / 128.f);
        const float var = sq * (1.f / 128.f) - mu * mu;
        muA[t] = mu; riA[t] = rsqrtf(var + 1e-5f);
    }
    __syncthreads();
    for (int e = t; e < 32 * 128; e += 256) {
        const int r = e >> 7, c = e & 127;
        xn[r][c] = f2bs((xr[r][c] - muA[r]) * riA[r] * n1_w[c] + n1_b[c]);
    }
    __syncthreads();
    const int wave = t >> 6, lane = t & 63, quad = lane >> 4, l15 = lane & 15;
    const float scale = 0.1767766952966369f;  // 1/sqrt(32)
    for (int jt = wave; jt < 48; jt += 4) {
        const int mt = jt & 1, nt = jt >> 1;
        f32x4 acc = {0.f, 0.f, 0.f, 0.f};
        if (nt < 16) {  // qv GEMM: A=xn, W=wqv (256 rows)
            const int n = nt * 16 + l15;
            for (int kt = 0; kt < 4; kt++) {
                bf16x8 a = *(const bf16x8*)&xn[mt * 16 + l15][kt * 32 + quad * 8];
                bf16x8 b = *(const bf16x8*)&wqv[n * C + kt * 32 + quad * 8];
                acc = __builtin_amdgcn_mfma_f32_16x16x32_bf16(a, b, acc, 0, 0, 0);
            }
            const float bias = qv_b[n];
            for (int r = 0; r < 4; r++) {
                const int m = mt * 16 + quad * 4 + r;
                const float v = acc[r] + bias;
                if (n < C) qb[(pix0 + m) * C + n] = __float2bfloat16(v * scale);
                else       vb[(pix0 + m) * C + (n - C)] = __float2bfloat16(v);
            }
        } else {       // k GEMM: A=yb, W=wk (128 rows)
            const int n = (nt - 16) * 16 + l15;
            for (int kt = 0; kt < 4; kt++) {
                bf16x8 a = *(const bf16x8*)&yb[mt * 16 + l15][kt * 32 + quad * 8];
                bf16x8 b = *(const bf16x8*)&wk[n * C + kt * 32 + quad * 8];
                acc = __builtin_amdgcn_mfma_f32_16x16x32_bf16(a, b, acc, 0, 0, 0);
            }
            const float bias = k_b[n];
            for (int r = 0; r < 4; r++) {
                const int m = mt * 16 + quad * 4 + r;
                kb[(pix0 + m) * C + n] = __float2bfloat16(acc[r] + bias);
            }
        }
    }
}

// ---------- kernel 2: NATTEN 7x7 attention + proj + residual (unchanged R3) ----------
__global__ __launch_bounds__(256) void k_attn_proj(
    const bf16* __restrict__ qb, const bf16* __restrict__ kb,
    const bf16* __restrict__ vb, const float* __restrict__ rpb,
    const float* __restrict__ proj_w, const float* __restrict__ proj_b,
    const float* __restrict__ x, float* __restrict__ x1out) {
    __shared__ float sq[HEADS][HD];
    __shared__ float sp[HEADS][64];
    __shared__ float aoL[C];
    const int pix = blockIdx.x;
    const int t = threadIdx.x;
    const int h = t >> 6;
    const int lane = t & 63;
    const int i = pix >> 7, j = pix & 127;
    int sh = i - 3; sh = sh < 0 ? 0 : (sh > HW - 7 ? HW - 7 : sh);
    int sw = j - 3; sw = sw < 0 ? 0 : (sw > HW - 7 ? HW - 7 : sw);
    if (lane < HD) sq[h][lane] = b2f(qb[pix * C + h * HD + lane]);
    __syncthreads();
    float logit = -1e30f;
    if (lane < 49) {
        const int a = lane / 7, c2 = lane % 7;
        const int ni = sh + a, nj = sw + c2;
        const bf16* kp = kb + (ni * HW + nj) * C + h * HD;
        float acc = 0.f;
#pragma unroll
        for (int d = 0; d < HD; d++) acc += sq[h][d] * b2f(kp[d]);
        acc += rpb[h * 169 + (ni - i + 6) * 13 + (nj - j + 6)];
        logit = acc;
    }
    const float mx = wave_max(logit);
    const float e = (lane < 49) ? __expf(logit - mx) : 0.f;
    const float s = wave_sum(e);
    sp[h][lane] = e / s;
    __syncthreads();
    if (lane < HD) {
        float acc = 0.f;
#pragma unroll
        for (int a = 0; a < 49; a++) {
            const int ni = sh + a / 7, nj = sw + a % 7;
            acc += sp[h][a] * b2f(vb[(ni * HW + nj) * C + h * HD + lane]);
        }
        aoL[h * HD + lane] = acc;
    }
    __syncthreads();
    if (t < C) {
        const float* wrow = proj_w + t * C;
        float acc = 0.f;
#pragma unroll 8
        for (int c = 0; c < C; c++) acc += aoL[c] * wrow[c];
        acc += proj_b[t] + x[pix * C + t];
        x1out[pix * C + t] = acc;
    }
}

// ---------- kernel 3: LN2 + FC1 + GELU + FC2 + residual, MFMA, 32 pixels/block ----------
__global__ __launch_bounds__(256) void k_mlp(
    float* __restrict__ io, const float* __restrict__ n2_w,
    const float* __restrict__ n2_b, const short* __restrict__ wfc1,
    const float* __restrict__ fc1_b, const short* __restrict__ wfc2,
    const float* __restrict__ fc2_b) {
    __shared__ float xr[32][132];
    __shared__ short xn[32][136];
    __shared__ short hb[32][520];   // 512 + 8 pad
    __shared__ float redS[32][8], redQ[32][8];
    __shared__ float muA[32], riA[32];
    const int t = threadIdx.x;
    const int pix0 = blockIdx.x * 32;
    for (int e = t; e < 32 * 128; e += 256) {
        const int r = e >> 7, c = e & 127;
        xr[r][c] = io[(pix0 + r) * C + c];
    }
    __syncthreads();
    {
        const int r = t >> 3, s = t & 7;
        float sm = 0.f, sq = 0.f;
        for (int i = 0; i < 16; i++) { float v = xr[r][s * 16 + i]; sm += v; sq += v * v; }
        redS[r][s] = sm; redQ[r][s] = sq;
    }
    __syncthreads();
    if (t < 32) {
        float sm = 0.f, sq = 0.f;
        for (int s = 0; s < 8; s++) { sm += redS[t][s]; sq += redQ[t][s]; }
        const float mu = sm * (1.f / 128.f);
        const float var = sq * (1.f / 128.f) - mu * mu;
        muA[t] = mu; riA[t] = rsqrtf(var + 1e-5f);
    }
    __syncthreads();
    for (int e = t; e < 32 * 128; e += 256) {
        const int r = e >> 7, c = e & 127;
        xn[r][c] = f2bs((xr[r][c] - muA[r]) * riA[r] * n2_w[c] + n2_b[c]);
    }
    __syncthreads();
    const int wave = t >> 6, lane = t & 63, quad = lane >> 4, l15 = lane & 15;
    // fc1 + gelu: [32x512] = xn[32x128] @ wfc1[512x128]^T
    for (int jt = wave; jt < 64; jt += 4) {
        const int mt = jt >> 5, nt = jt & 31;
        const int n = nt * 16 + l15;
        f32x4 acc = {0.f, 0.f, 0.f, 0.f};
        for (int kt = 0; kt < 4; kt++) {
            bf16x8 a = *(const bf16x8*)&xn[mt * 16 + l15][kt * 32 + quad * 8];
            bf16x8 b = *(const bf16x8*)&wfc1[n * C + kt * 32 + quad * 8];
            acc = __builtin_amdgcn_mfma_f32_16x16x32_bf16(a, b, acc, 0, 0, 0);
        }
        const float bias = fc1_b[n];
        for (int r = 0; r < 4; r++) {
            const int m = mt * 16 + quad * 4 + r;
            float v = acc[r] + bias;
            v = 0.5f * v * (1.f + erff(v * 0.70710678118654752f));
            hb[m][n] = f2bs(v);
        }
    }
    __syncthreads();
    // fc2 + residual: [32x128] = hb[32x512] @ wfc2[128x512]^T
    for (int jt = wave; jt < 16; jt += 4) {
        const int mt = jt >> 3, nt = jt & 7;
        const int n = nt * 16 + l15;
        f32x4 acc = {0.f, 0.f, 0.f, 0.f};
        for (int kt = 0; kt < 16; kt++) {
            bf16x8 a = *(const bf16x8*)&hb[mt * 16 + l15][kt * 32 + quad * 8];
            bf16x8 b = *(const bf16x8*)&wfc2[n * 512 + kt * 32 + quad * 8];
            acc = __builtin_amdgcn_mfma_f32_16x16x32_bf16(a, b, acc, 0, 0, 0);
        }
        const float bias = fc2_b[n];
        for (int r = 0; r < 4; r++) {
            const int m = mt * 16 + quad * 4 + r;
            io[(pix0 + m) * C + n] = acc[r] + bias + xr[m][n];
        }
    }
}

extern "C" void kernel_launch(void* const* d_in, const int* in_sizes, int n_in,
                              void* d_out, int out_size, void* d_ws, size_t ws_size,
                              hipStream_t stream) {
    const float* x      = (const float*)d_in[0];
    const float* y      = (const float*)d_in[1];
    const float* qv_w   = (const float*)d_in[2];
    const float* qv_b   = (const float*)d_in[3];
    const float* k_w    = (const float*)d_in[4];
    const float* k_b    = (const float*)d_in[5];
    const float* rpb    = (const float*)d_in[6];
    const float* proj_w = (const float*)d_in[7];
    const float* proj_b = (const float*)d_in[8];
    const float* n1_w   = (const float*)d_in[9];
    const float* n1_b   = (const float*)d_in[10];
    const float* n2_w   = (const float*)d_in[11];
    const float* n2_b   = (const float*)d_in[12];
    const float* fc1_w  = (const float*)d_in[13];
    const float* fc1_b  = (const float*)d_in[14];
    const float* fc2_w  = (const float*)d_in[15];
    const float* fc2_b  = (const float*)d_in[16];
    float* out = (float*)d_out;

    bf16* qb  = (bf16*)d_ws;                        // 2M elems (4 MB)
    bf16* vb  = qb + (size_t)N_PIX * C;
    bf16* kb  = vb + (size_t)N_PIX * C;
    short* wqv  = (short*)(kb + (size_t)N_PIX * C); // 32768
    short* wk   = wqv + 32768;                      // 16384
    short* wfc1 = wk + 16384;                       // 65536
    short* wfc2 = wfc1 + 65536;                     // 65536  (total 12.34 MB)

    k_wconv<<<256, 256, 0, stream>>>(qv_w, k_w, fc1_w, fc2_w, wqv, wk, wfc1, wfc2);
    k_qkv<<<N_PIX / 32, 256, 0, stream>>>(x, y, wqv, qv_b, wk, k_b, n1_w, n1_b, qb, vb, kb);
    k_attn_proj<<<N_PIX, 256, 0, stream>>>(qb, kb, vb, rpb, proj_w, proj_b, x, out);
    k_mlp<<<N_PIX / 32, 256, 0, stream>>>(out, n2_w, n2_b, wfc1, fc1_b, wfc2, fc2_b);
}

// Round 5
// 212.088 us; speedup vs baseline: 8.6607x; 1.5403x over previous
//
#include <hip/hip_runtime.h>
#include <hip/hip_bf16.h>

// CrossNATBlock2D: B=1, H=W=128, C=128, HEADS=4, HD=32, K=7  (fp32 I/O)
// R5: k_attn stages K/V 7x7 windows in LDS (coalesced), writes ao bf16 aliased
// onto qb. k_mlp2 fuses proj(MFMA)+residual+LN2+FC1+GELU+FC2+residual; x1 never
// touches global. ws = qb/vb/kb (12 MB) + bf16 weights (384 KB).

#define N_PIX 16384
#define C 128
#define HEADS 4
#define HD 32
#define HW 128

typedef __hip_bfloat16 bf16;
typedef __attribute__((ext_vector_type(8))) short bf16x8;
typedef __attribute__((ext_vector_type(4))) float f32x4;

__device__ __forceinline__ float b2f(bf16 v) { return __bfloat162float(v); }
__device__ __forceinline__ short f2bs(float f) {
    bf16 h = __float2bfloat16(f);
    return (short)__bfloat16_as_ushort(h);
}

__device__ __forceinline__ float wave_sum(float v) {
    for (int m = 1; m < 64; m <<= 1) v += __shfl_xor(v, m, 64);
    return v;
}
__device__ __forceinline__ float wave_max(float v) {
    for (int m = 1; m < 64; m <<= 1) v = fmaxf(v, __shfl_xor(v, m, 64));
    return v;
}

// ---------- kernel 0: convert weights fp32 -> bf16 into ws ----------
__global__ __launch_bounds__(256) void k_wconv(
    const float* __restrict__ qv_w, const float* __restrict__ k_w,
    const float* __restrict__ proj_w, const float* __restrict__ fc1_w,
    const float* __restrict__ fc2_w,
    short* __restrict__ wqv, short* __restrict__ wk, short* __restrict__ wproj,
    short* __restrict__ wfc1, short* __restrict__ wfc2) {
    const int i = blockIdx.x * 256 + threadIdx.x;
    if (i < 32768) wqv[i] = f2bs(qv_w[i]);
    if (i < 16384) { wk[i] = f2bs(k_w[i]); wproj[i] = f2bs(proj_w[i]); }
    if (i < 65536) { wfc1[i] = f2bs(fc1_w[i]); wfc2[i] = f2bs(fc2_w[i]); }
}

// ---------- kernel 1: LN1 + QV GEMM + K proj, MFMA, 32 pixels/block ----------
__global__ __launch_bounds__(256) void k_qkv(
    const float* __restrict__ x, const float* __restrict__ y,
    const short* __restrict__ wqv, const float* __restrict__ qv_b,
    const short* __restrict__ wk, const float* __restrict__ k_b,
    const float* __restrict__ n1_w, const float* __restrict__ n1_b,
    bf16* __restrict__ qb, bf16* __restrict__ vb, bf16* __restrict__ kb) {
    __shared__ float xr[32][132];
    __shared__ short xn[32][136];
    __shared__ short yb[32][136];
    __shared__ float redS[32][8], redQ[32][8];
    __shared__ float muA[32], riA[32];
    const int t = threadIdx.x;
    const int pix0 = blockIdx.x * 32;
    for (int e = t; e < 32 * 128; e += 256) {
        const int r = e >> 7, c = e & 127;
        xr[r][c] = x[(pix0 + r) * C + c];
        yb[r][c] = f2bs(y[(pix0 + r) * C + c]);
    }
    __syncthreads();
    {
        const int r = t >> 3, s = t & 7;
        float sm = 0.f, sq = 0.f;
        for (int i = 0; i < 16; i++) { float v = xr[r][s * 16 + i]; sm += v; sq += v * v; }
        redS[r][s] = sm; redQ[r][s] = sq;
    }
    __syncthreads();
    if (t < 32) {
        float sm = 0.f, sq = 0.f;
        for (int s = 0; s < 8; s++) { sm += redS[t][s]; sq += redQ[t][s]; }
        const float mu = sm * (1.f / 128.f);
        const float var = sq * (1.f / 128.f) - mu * mu;
        muA[t] = mu; riA[t] = rsqrtf(var + 1e-5f);
    }
    __syncthreads();
    for (int e = t; e < 32 * 128; e += 256) {
        const int r = e >> 7, c = e & 127;
        xn[r][c] = f2bs((xr[r][c] - muA[r]) * riA[r] * n1_w[c] + n1_b[c]);
    }
    __syncthreads();
    const int wave = t >> 6, lane = t & 63, quad = lane >> 4, l15 = lane & 15;
    const float scale = 0.1767766952966369f;  // 1/sqrt(32)
    for (int jt = wave; jt < 48; jt += 4) {
        const int mt = jt & 1, nt = jt >> 1;
        f32x4 acc = {0.f, 0.f, 0.f, 0.f};
        if (nt < 16) {  // qv GEMM
            const int n = nt * 16 + l15;
            for (int kt = 0; kt < 4; kt++) {
                bf16x8 a = *(const bf16x8*)&xn[mt * 16 + l15][kt * 32 + quad * 8];
                bf16x8 b = *(const bf16x8*)&wqv[n * C + kt * 32 + quad * 8];
                acc = __builtin_amdgcn_mfma_f32_16x16x32_bf16(a, b, acc, 0, 0, 0);
            }
            const float bias = qv_b[n];
            for (int r = 0; r < 4; r++) {
                const int m = mt * 16 + quad * 4 + r;
                const float v = acc[r] + bias;
                if (n < C) qb[(pix0 + m) * C + n] = __float2bfloat16(v * scale);
                else       vb[(pix0 + m) * C + (n - C)] = __float2bfloat16(v);
            }
        } else {       // k GEMM
            const int n = (nt - 16) * 16 + l15;
            for (int kt = 0; kt < 4; kt++) {
                bf16x8 a = *(const bf16x8*)&yb[mt * 16 + l15][kt * 32 + quad * 8];
                bf16x8 b = *(const bf16x8*)&wk[n * C + kt * 32 + quad * 8];
                acc = __builtin_amdgcn_mfma_f32_16x16x32_bf16(a, b, acc, 0, 0, 0);
            }
            const float bias = k_b[n];
            for (int r = 0; r < 4; r++) {
                const int m = mt * 16 + quad * 4 + r;
                kb[(pix0 + m) * C + n] = __float2bfloat16(acc[r] + bias);
            }
        }
    }
}

// ---------- kernel 2: NATTEN 7x7 attention from LDS-staged windows ----------
// ao may alias qb (each block reads only its own pixel's q, then writes ao last)
__global__ __launch_bounds__(256) void k_attn(
    const bf16* qb, const bf16* __restrict__ kb,
    const bf16* __restrict__ vb, const float* __restrict__ rpb,
    bf16* ao) {
    __shared__ bf16 Kl[49][136];
    __shared__ bf16 Vl[49][136];
    __shared__ float sq[HEADS][HD];
    __shared__ float sp[HEADS][64];
    const int pix = blockIdx.x;
    const int t = threadIdx.x;
    const int h = t >> 6, lane = t & 63;
    const int i = pix >> 7, j = pix & 127;
    int sh = i - 3; sh = sh < 0 ? 0 : (sh > HW - 7 ? HW - 7 : sh);
    int sw = j - 3; sw = sw < 0 ? 0 : (sw > HW - 7 ? HW - 7 : sw);
    if (t < 128) sq[t >> 5][t & 31] = b2f(qb[pix * C + t]);
    // stage K and V windows: 49 rows x 16 x 16B x 2 tensors
    for (int u = t; u < 49 * 16 * 2; u += 256) {
        const int tv = (u >= 784) ? 1 : 0;
        const int r = (tv ? u - 784 : u) >> 4;
        const int seg = u & 15;
        const int p = (sh + r / 7) * HW + (sw + r % 7);
        const uint4 d = *(const uint4*)((tv ? vb : kb) + (size_t)p * C + seg * 8);
        if (tv) *(uint4*)&Vl[r][seg * 8] = d;
        else    *(uint4*)&Kl[r][seg * 8] = d;
    }
    __syncthreads();
    float logit = -1e30f;
    if (lane < 49) {
        const int ni = sh + lane / 7, nj = sw + lane % 7;
        float acc = 0.f;
#pragma unroll
        for (int d = 0; d < HD; d++) acc += sq[h][d] * b2f(Kl[lane][h * HD + d]);
        logit = acc + rpb[h * 169 + (ni - i + 6) * 13 + (nj - j + 6)];
    }
    const float mx = wave_max(logit);
    const float e = (lane < 49) ? __expf(logit - mx) : 0.f;
    const float s = wave_sum(e);
    sp[h][lane] = e / s;
    __syncthreads();
    if (lane < HD) {
        float acc = 0.f;
#pragma unroll
        for (int a = 0; a < 49; a++) acc += sp[h][a] * b2f(Vl[a][h * HD + lane]);
        ao[pix * C + h * HD + lane] = __float2bfloat16(acc);
    }
}

// ---------- kernel 3: proj + residual + LN2 + FC1 + GELU + FC2 + residual ----------
__global__ __launch_bounds__(256) void k_mlp2(
    const float* __restrict__ x, const bf16* __restrict__ ao,
    const short* __restrict__ wproj, const float* __restrict__ proj_b,
    const float* __restrict__ n2_w, const float* __restrict__ n2_b,
    const short* __restrict__ wfc1, const float* __restrict__ fc1_b,
    const short* __restrict__ wfc2, const float* __restrict__ fc2_b,
    float* __restrict__ out) {
    __shared__ float xr[32][132];     // x, then x1 in place
    __shared__ short aos[32][136];
    __shared__ short xn[32][136];
    __shared__ short hb[32][520];
    __shared__ float redS[32][8], redQ[32][8];
    __shared__ float muA[32], riA[32];
    const int t = threadIdx.x;
    const int pix0 = blockIdx.x * 32;
    for (int e = t; e < 32 * 128; e += 256) {
        const int r = e >> 7, c = e & 127;
        xr[r][c] = x[(pix0 + r) * C + c];
    }
    for (int u = t; u < 32 * 16; u += 256) {
        const int r = u >> 4, seg = u & 15;
        *(uint4*)&aos[r][seg * 8] = *(const uint4*)(ao + (size_t)(pix0 + r) * C + seg * 8);
    }
    __syncthreads();
    const int wave = t >> 6, lane = t & 63, quad = lane >> 4, l15 = lane & 15;
    // proj MFMA: x1 = x + aos @ wproj^T + proj_b  (into xr in place)
    for (int jt = wave; jt < 16; jt += 4) {
        const int mt = jt >> 3, nt = jt & 7;
        const int n = nt * 16 + l15;
        f32x4 acc = {0.f, 0.f, 0.f, 0.f};
        for (int kt = 0; kt < 4; kt++) {
            bf16x8 a = *(const bf16x8*)&aos[mt * 16 + l15][kt * 32 + quad * 8];
            bf16x8 b = *(const bf16x8*)&wproj[n * C + kt * 32 + quad * 8];
            acc = __builtin_amdgcn_mfma_f32_16x16x32_bf16(a, b, acc, 0, 0, 0);
        }
        const float bias = proj_b[n];
        for (int r = 0; r < 4; r++) {
            const int m = mt * 16 + quad * 4 + r;
            xr[m][n] += acc[r] + bias;
        }
    }
    __syncthreads();
    {
        const int r = t >> 3, s = t & 7;
        float sm = 0.f, sq = 0.f;
        for (int i = 0; i < 16; i++) { float v = xr[r][s * 16 + i]; sm += v; sq += v * v; }
        redS[r][s] = sm; redQ[r][s] = sq;
    }
    __syncthreads();
    if (t < 32) {
        float sm = 0.f, sq = 0.f;
        for (int s = 0; s < 8; s++) { sm += redS[t][s]; sq += redQ[t][s]; }
        const float mu = sm * (1.f / 128.f);
        const float var = sq * (1.f / 128.f) - mu * mu;
        muA[t] = mu; riA[t] = rsqrtf(var + 1e-5f);
    }
    __syncthreads();
    for (int e = t; e < 32 * 128; e += 256) {
        const int r = e >> 7, c = e & 127;
        xn[r][c] = f2bs((xr[r][c] - muA[r]) * riA[r] * n2_w[c] + n2_b[c]);
    }
    __syncthreads();
    // fc1 + gelu
    for (int jt = wave; jt < 64; jt += 4) {
        const int mt = jt >> 5, nt = jt & 31;
        const int n = nt * 16 + l15;
        f32x4 acc = {0.f, 0.f, 0.f, 0.f};
        for (int kt = 0; kt < 4; kt++) {
            bf16x8 a = *(const bf16x8*)&xn[mt * 16 + l15][kt * 32 + quad * 8];
            bf16x8 b = *(const bf16x8*)&wfc1[n * C + kt * 32 + quad * 8];
            acc = __builtin_amdgcn_mfma_f32_16x16x32_bf16(a, b, acc, 0, 0, 0);
        }
        const float bias = fc1_b[n];
        for (int r = 0; r < 4; r++) {
            const int m = mt * 16 + quad * 4 + r;
            float v = acc[r] + bias;
            v = 0.5f * v * (1.f + erff(v * 0.70710678118654752f));
            hb[m][n] = f2bs(v);
        }
    }
    __syncthreads();
    // fc2 + residual -> out
    for (int jt = wave; jt < 16; jt += 4) {
        const int mt = jt >> 3, nt = jt & 7;
        const int n = nt * 16 + l15;
        f32x4 acc = {0.f, 0.f, 0.f, 0.f};
        for (int kt = 0; kt < 16; kt++) {
            bf16x8 a = *(const bf16x8*)&hb[mt * 16 + l15][kt * 32 + quad * 8];
            bf16x8 b = *(const bf16x8*)&wfc2[n * 512 + kt * 32 + quad * 8];
            acc = __builtin_amdgcn_mfma_f32_16x16x32_bf16(a, b, acc, 0, 0, 0);
        }
        const float bias = fc2_b[n];
        for (int r = 0; r < 4; r++) {
            const int m = mt * 16 + quad * 4 + r;
            out[(pix0 + m) * C + n] = acc[r] + bias + xr[m][n];
        }
    }
}

extern "C" void kernel_launch(void* const* d_in, const int* in_sizes, int n_in,
                              void* d_out, int out_size, void* d_ws, size_t ws_size,
                              hipStream_t stream) {
    const float* x      = (const float*)d_in[0];
    const float* y      = (const float*)d_in[1];
    const float* qv_w   = (const float*)d_in[2];
    const float* qv_b   = (const float*)d_in[3];
    const float* k_w    = (const float*)d_in[4];
    const float* k_b    = (const float*)d_in[5];
    const float* rpb    = (const float*)d_in[6];
    const float* proj_w = (const float*)d_in[7];
    const float* proj_b = (const float*)d_in[8];
    const float* n1_w   = (const float*)d_in[9];
    const float* n1_b   = (const float*)d_in[10];
    const float* n2_w   = (const float*)d_in[11];
    const float* n2_b   = (const float*)d_in[12];
    const float* fc1_w  = (const float*)d_in[13];
    const float* fc1_b  = (const float*)d_in[14];
    const float* fc2_w  = (const float*)d_in[15];
    const float* fc2_b  = (const float*)d_in[16];
    float* out = (float*)d_out;

    bf16* qb  = (bf16*)d_ws;                        // 2M elems; later reused as ao
    bf16* vb  = qb + (size_t)N_PIX * C;
    bf16* kb  = vb + (size_t)N_PIX * C;
    short* wqv  = (short*)(kb + (size_t)N_PIX * C); // 32768
    short* wk   = wqv + 32768;                      // 16384
    short* wproj= wk + 16384;                       // 16384
    short* wfc1 = wproj + 16384;                    // 65536
    short* wfc2 = wfc1 + 65536;                     // 65536  (total ~12.4 MB)
    bf16* ao = qb;                                  // alias: safe (see k_attn)

    k_wconv<<<256, 256, 0, stream>>>(qv_w, k_w, proj_w, fc1_w, fc2_w,
                                     wqv, wk, wproj, wfc1, wfc2);
    k_qkv<<<N_PIX / 32, 256, 0, stream>>>(x, y, wqv, qv_b, wk, k_b, n1_w, n1_b, qb, vb, kb);
    k_attn<<<N_PIX, 256, 0, stream>>>(qb, kb, vb, rpb, ao);
    k_mlp2<<<N_PIX / 32, 256, 0, stream>>>(x, ao, wproj, proj_b, n2_w, n2_b,
                                           wfc1, fc1_b, wfc2, fc2_b, out);
}

// Round 6
// 179.245 us; speedup vs baseline: 10.2476x; 1.1832x over previous
//
#include <hip/hip_runtime.h>
#include <hip/hip_bf16.h>

// CrossNATBlock2D: B=1, H=W=128, C=128, HEADS=4, HD=32, K=7  (fp32 I/O)
// R6: k_attn rewritten as MFMA neighborhood-GEMM over 2x8 pixel tiles.
// Union window = 8x14 = 112 neighbors staged once per block (16x reuse).
// P aliases the dead K LDS buffer (barriers). ao aliases qb in ws (safe:
// block reads only its own pixels' q, all reads barrier-ordered before writes).

#define N_PIX 16384
#define C 128
#define HEADS 4
#define HD 32
#define HW 128

typedef __hip_bfloat16 bf16;
typedef __attribute__((ext_vector_type(8))) short bf16x8;
typedef __attribute__((ext_vector_type(4))) float f32x4;

__device__ __forceinline__ float b2f(bf16 v) { return __bfloat162float(v); }
__device__ __forceinline__ short f2bs(float f) {
    bf16 h = __float2bfloat16(f);
    return (short)__bfloat16_as_ushort(h);
}
__device__ __forceinline__ float bs2f(short s) {
    __hip_bfloat16_raw r; r.x = (unsigned short)s;
    return __bfloat162float(__hip_bfloat16(r));
}

// ---------- kernel 0: convert weights fp32 -> bf16 into ws ----------
__global__ __launch_bounds__(256) void k_wconv(
    const float* __restrict__ qv_w, const float* __restrict__ k_w,
    const float* __restrict__ proj_w, const float* __restrict__ fc1_w,
    const float* __restrict__ fc2_w,
    short* __restrict__ wqv, short* __restrict__ wk, short* __restrict__ wproj,
    short* __restrict__ wfc1, short* __restrict__ wfc2) {
    const int i = blockIdx.x * 256 + threadIdx.x;
    if (i < 32768) wqv[i] = f2bs(qv_w[i]);
    if (i < 16384) { wk[i] = f2bs(k_w[i]); wproj[i] = f2bs(proj_w[i]); }
    if (i < 65536) { wfc1[i] = f2bs(fc1_w[i]); wfc2[i] = f2bs(fc2_w[i]); }
}

// ---------- kernel 1: LN1 + QV GEMM + K proj, MFMA, 32 pixels/block ----------
__global__ __launch_bounds__(256) void k_qkv(
    const float* __restrict__ x, const float* __restrict__ y,
    const short* __restrict__ wqv, const float* __restrict__ qv_b,
    const short* __restrict__ wk, const float* __restrict__ k_b,
    const float* __restrict__ n1_w, const float* __restrict__ n1_b,
    bf16* __restrict__ qb, bf16* __restrict__ vb, bf16* __restrict__ kb) {
    __shared__ float xr[32][132];
    __shared__ short xn[32][136];
    __shared__ short yb[32][136];
    __shared__ float redS[32][8], redQ[32][8];
    __shared__ float muA[32], riA[32];
    const int t = threadIdx.x;
    const int pix0 = blockIdx.x * 32;
    for (int e = t; e < 32 * 128; e += 256) {
        const int r = e >> 7, c = e & 127;
        xr[r][c] = x[(pix0 + r) * C + c];
        yb[r][c] = f2bs(y[(pix0 + r) * C + c]);
    }
    __syncthreads();
    {
        const int r = t >> 3, s = t & 7;
        float sm = 0.f, sq = 0.f;
        for (int i = 0; i < 16; i++) { float v = xr[r][s * 16 + i]; sm += v; sq += v * v; }
        redS[r][s] = sm; redQ[r][s] = sq;
    }
    __syncthreads();
    if (t < 32) {
        float sm = 0.f, sq = 0.f;
        for (int s = 0; s < 8; s++) { sm += redS[t][s]; sq += redQ[t][s]; }
        const float mu = sm * (1.f / 128.f);
        const float var = sq * (1.f / 128.f) - mu * mu;
        muA[t] = mu; riA[t] = rsqrtf(var + 1e-5f);
    }
    __syncthreads();
    for (int e = t; e < 32 * 128; e += 256) {
        const int r = e >> 7, c = e & 127;
        xn[r][c] = f2bs((xr[r][c] - muA[r]) * riA[r] * n1_w[c] + n1_b[c]);
    }
    __syncthreads();
    const int wave = t >> 6, lane = t & 63, quad = lane >> 4, l15 = lane & 15;
    const float scale = 0.1767766952966369f;  // 1/sqrt(32)
    for (int jt = wave; jt < 48; jt += 4) {
        const int mt = jt & 1, nt = jt >> 1;
        f32x4 acc = {0.f, 0.f, 0.f, 0.f};
        if (nt < 16) {  // qv GEMM
            const int n = nt * 16 + l15;
            for (int kt = 0; kt < 4; kt++) {
                bf16x8 a = *(const bf16x8*)&xn[mt * 16 + l15][kt * 32 + quad * 8];
                bf16x8 b = *(const bf16x8*)&wqv[n * C + kt * 32 + quad * 8];
                acc = __builtin_amdgcn_mfma_f32_16x16x32_bf16(a, b, acc, 0, 0, 0);
            }
            const float bias = qv_b[n];
            for (int r = 0; r < 4; r++) {
                const int m = mt * 16 + quad * 4 + r;
                const float v = acc[r] + bias;
                if (n < C) qb[(pix0 + m) * C + n] = __float2bfloat16(v * scale);
                else       vb[(pix0 + m) * C + (n - C)] = __float2bfloat16(v);
            }
        } else {       // k GEMM
            const int n = (nt - 16) * 16 + l15;
            for (int kt = 0; kt < 4; kt++) {
                bf16x8 a = *(const bf16x8*)&yb[mt * 16 + l15][kt * 32 + quad * 8];
                bf16x8 b = *(const bf16x8*)&wk[n * C + kt * 32 + quad * 8];
                acc = __builtin_amdgcn_mfma_f32_16x16x32_bf16(a, b, acc, 0, 0, 0);
            }
            const float bias = k_b[n];
            for (int r = 0; r < 4; r++) {
                const int m = mt * 16 + quad * 4 + r;
                kb[(pix0 + m) * C + n] = __float2bfloat16(acc[r] + bias);
            }
        }
    }
}

// ---------- kernel 2: NATTEN 7x7 MFMA attention, 2x8 pixel tile per block ----------
// ao may alias qb: all q reads complete (block-wide barriers) before ao writes;
// blocks touch disjoint pixels; q/ao channel ranges per wave are the same head.
__global__ __launch_bounds__(256) void k_attn(
    const bf16* qb, const bf16* __restrict__ kb,
    const bf16* __restrict__ vb, const float* __restrict__ rpb,
    bf16* ao) {
    __shared__ short KP[112 * 136];   // K during QK^T, then P[4][16][136]
    __shared__ short Vl[112 * 136];
    __shared__ short rpbL[676];
    const int t = threadIdx.x;
    const int h = t >> 6, lane = t & 63, quad = lane >> 4, l15 = lane & 15;
    const int i0 = (blockIdx.x >> 4) * 2;      // 64 row-tiles
    const int j0 = (blockIdx.x & 15) * 8;      // 16 col-tiles
    const int rs = min(max(i0 - 3, 0), 120);   // union rows [rs, rs+7]
    const int cs = min(max(j0 - 3, 0), 114);   // union cols [cs, cs+13]
    // stage K and V union windows (112 rows x 128 ch, 16B chunks)
    for (int u = t; u < 112 * 16 * 2; u += 256) {
        const int tv = (u >= 1792) ? 1 : 0;
        const int uu = tv ? u - 1792 : u;
        const int r = uu >> 4, seg = uu & 15;
        const int wr = r / 14, wc = r % 14;
        const size_t g = (size_t)((rs + wr) * HW + cs + wc) * C + seg * 8;
        const uint4 d = *(const uint4*)((tv ? vb : kb) + g);
        *(uint4*)&(tv ? Vl : KP)[r * 136 + seg * 8] = d;
    }
    for (int u = t; u < 676; u += 256) rpbL[u] = f2bs(rpb[u]);
    __syncthreads();
    // ---- QK^T: S[16 pixels][112 nbrs], per wave = head ----
    const int mA = l15;                            // A-frag row = pixel
    const int pA = (i0 + (mA >> 3)) * HW + j0 + (mA & 7);
    const bf16x8 aQ = *(const bf16x8*)(qb + (size_t)pA * C + h * HD + quad * 8);
    f32x4 S[7];
    for (int nt = 0; nt < 7; nt++) {
        const bf16x8 bK = *(const bf16x8*)&KP[(nt * 16 + l15) * 136 + h * HD + quad * 8];
        f32x4 z = {0.f, 0.f, 0.f, 0.f};
        S[nt] = __builtin_amdgcn_mfma_f32_16x16x32_bf16(aQ, bK, z, 0, 0, 0);
    }
    // ---- bias + validity mask (C-layout: row=quad*4+r, col=nt*16+l15) ----
    float mx[4], sm[4];
    for (int r = 0; r < 4; r++) {
        const int m = quad * 4 + r;
        const int i = i0 + (m >> 3), j = j0 + (m & 7);
        const int shi = min(max(i - 3, 0), 121);
        const int swj = min(max(j - 3, 0), 121);
        float best = -1e30f;
        for (int nt = 0; nt < 7; nt++) {
            const int nb = nt * 16 + l15;
            const int wr = nb / 14, wc = nb % 14;
            const int ai = rs + wr, aj = cs + wc;
            const bool valid = (ai >= shi) & (ai <= shi + 6) & (aj >= swj) & (aj <= swj + 6);
            const int ri = min(max(ai - i + 6, 0), 12);
            const int rj = min(max(aj - j + 6, 0), 12);
            const float bias = bs2f(rpbL[h * 169 + ri * 13 + rj]);
            const float v = valid ? (S[nt][r] + bias) : -1e30f;
            S[nt][r] = v;
            best = fmaxf(best, v);
        }
        for (int msk = 1; msk < 16; msk <<= 1) best = fmaxf(best, __shfl_xor(best, msk, 64));
        mx[r] = best;
        float s = 0.f;
        for (int nt = 0; nt < 7; nt++) {
            const float e = __expf(S[nt][r] - best);
            S[nt][r] = e;
            s += e;
        }
        for (int msk = 1; msk < 16; msk <<= 1) s += __shfl_xor(s, msk, 64);
        sm[r] = 1.f / s;
    }
    __syncthreads();   // all waves done reading KP as K
    // ---- write P (bf16) over KP: P[h][16][136], zero pad cols 112..127 ----
    for (int r = 0; r < 4; r++) {
        short* prow = &KP[(h * 16 + quad * 4 + r) * 136];
        for (int nt = 0; nt < 7; nt++)
            prow[nt * 16 + l15] = f2bs(S[nt][r] * sm[r]);
        prow[112 + l15] = 0;
    }
    __syncthreads();
    // ---- PV: out[16][32] per head ----
    f32x4 O0 = {0.f, 0.f, 0.f, 0.f}, O1 = {0.f, 0.f, 0.f, 0.f};
    for (int kt = 0; kt < 4; kt++) {
        const bf16x8 aP = *(const bf16x8*)&KP[(h * 16 + l15) * 136 + kt * 32 + quad * 8];
        for (int nt2 = 0; nt2 < 2; nt2++) {
            bf16x8 bV;
            const int ch = h * HD + nt2 * 16 + l15;
#pragma unroll
            for (int jj = 0; jj < 8; jj++) {
                const int nbr = kt * 32 + quad * 8 + jj;
                bV[jj] = (nbr < 112) ? Vl[nbr * 136 + ch] : (short)0;
            }
            if (nt2 == 0) O0 = __builtin_amdgcn_mfma_f32_16x16x32_bf16(aP, bV, O0, 0, 0, 0);
            else          O1 = __builtin_amdgcn_mfma_f32_16x16x32_bf16(aP, bV, O1, 0, 0, 0);
        }
    }
    for (int r = 0; r < 4; r++) {
        const int m = quad * 4 + r;
        const int p = (i0 + (m >> 3)) * HW + j0 + (m & 7);
        ao[(size_t)p * C + h * HD + l15] = __float2bfloat16(O0[r]);
        ao[(size_t)p * C + h * HD + 16 + l15] = __float2bfloat16(O1[r]);
    }
}

// ---------- kernel 3: proj + residual + LN2 + FC1 + GELU + FC2 + residual ----------
__global__ __launch_bounds__(256) void k_mlp2(
    const float* __restrict__ x, const bf16* __restrict__ ao,
    const short* __restrict__ wproj, const float* __restrict__ proj_b,
    const float* __restrict__ n2_w, const float* __restrict__ n2_b,
    const short* __restrict__ wfc1, const float* __restrict__ fc1_b,
    const short* __restrict__ wfc2, const float* __restrict__ fc2_b,
    float* __restrict__ out) {
    __shared__ float xr[32][132];     // x, then x1 in place
    __shared__ short aos[32][136];
    __shared__ short xn[32][136];
    __shared__ short hb[32][520];
    __shared__ float redS[32][8], redQ[32][8];
    __shared__ float muA[32], riA[32];
    const int t = threadIdx.x;
    const int pix0 = blockIdx.x * 32;
    for (int e = t; e < 32 * 128; e += 256) {
        const int r = e >> 7, c = e & 127;
        xr[r][c] = x[(pix0 + r) * C + c];
    }
    for (int u = t; u < 32 * 16; u += 256) {
        const int r = u >> 4, seg = u & 15;
        *(uint4*)&aos[r][seg * 8] = *(const uint4*)(ao + (size_t)(pix0 + r) * C + seg * 8);
    }
    __syncthreads();
    const int wave = t >> 6, lane = t & 63, quad = lane >> 4, l15 = lane & 15;
    for (int jt = wave; jt < 16; jt += 4) {
        const int mt = jt >> 3, nt = jt & 7;
        const int n = nt * 16 + l15;
        f32x4 acc = {0.f, 0.f, 0.f, 0.f};
        for (int kt = 0; kt < 4; kt++) {
            bf16x8 a = *(const bf16x8*)&aos[mt * 16 + l15][kt * 32 + quad * 8];
            bf16x8 b = *(const bf16x8*)&wproj[n * C + kt * 32 + quad * 8];
            acc = __builtin_amdgcn_mfma_f32_16x16x32_bf16(a, b, acc, 0, 0, 0);
        }
        const float bias = proj_b[n];
        for (int r = 0; r < 4; r++) {
            const int m = mt * 16 + quad * 4 + r;
            xr[m][n] += acc[r] + bias;
        }
    }
    __syncthreads();
    {
        const int r = t >> 3, s = t & 7;
        float sm = 0.f, sq = 0.f;
        for (int i = 0; i < 16; i++) { float v = xr[r][s * 16 + i]; sm += v; sq += v * v; }
        redS[r][s] = sm; redQ[r][s] = sq;
    }
    __syncthreads();
    if (t < 32) {
        float sm = 0.f, sq = 0.f;
        for (int s = 0; s < 8; s++) { sm += redS[t][s]; sq += redQ[t][s]; }
        const float mu = sm * (1.f / 128.f);
        const float var = sq * (1.f / 128.f) - mu * mu;
        muA[t] = mu; riA[t] = rsqrtf(var + 1e-5f);
    }
    __syncthreads();
    for (int e = t; e < 32 * 128; e += 256) {
        const int r = e >> 7, c = e & 127;
        xn[r][c] = f2bs((xr[r][c] - muA[r]) * riA[r] * n2_w[c] + n2_b[c]);
    }
    __syncthreads();
    for (int jt = wave; jt < 64; jt += 4) {
        const int mt = jt >> 5, nt = jt & 31;
        const int n = nt * 16 + l15;
        f32x4 acc = {0.f, 0.f, 0.f, 0.f};
        for (int kt = 0; kt < 4; kt++) {
            bf16x8 a = *(const bf16x8*)&xn[mt * 16 + l15][kt * 32 + quad * 8];
            bf16x8 b = *(const bf16x8*)&wfc1[n * C + kt * 32 + quad * 8];
            acc = __builtin_amdgcn_mfma_f32_16x16x32_bf16(a, b, acc, 0, 0, 0);
        }
        const float bias = fc1_b[n];
        for (int r = 0; r < 4; r++) {
            const int m = mt * 16 + quad * 4 + r;
            float v = acc[r] + bias;
            v = 0.5f * v * (1.f + erff(v * 0.70710678118654752f));
            hb[m][n] = f2bs(v);
        }
    }
    __syncthreads();
    for (int jt = wave; jt < 16; jt += 4) {
        const int mt = jt >> 3, nt = jt & 7;
        const int n = nt * 16 + l15;
        f32x4 acc = {0.f, 0.f, 0.f, 0.f};
        for (int kt = 0; kt < 16; kt++) {
            bf16x8 a = *(const bf16x8*)&hb[mt * 16 + l15][kt * 32 + quad * 8];
            bf16x8 b = *(const bf16x8*)&wfc2[n * 512 + kt * 32 + quad * 8];
            acc = __builtin_amdgcn_mfma_f32_16x16x32_bf16(a, b, acc, 0, 0, 0);
        }
        const float bias = fc2_b[n];
        for (int r = 0; r < 4; r++) {
            const int m = mt * 16 + quad * 4 + r;
            out[(pix0 + m) * C + n] = acc[r] + bias + xr[m][n];
        }
    }
}

extern "C" void kernel_launch(void* const* d_in, const int* in_sizes, int n_in,
                              void* d_out, int out_size, void* d_ws, size_t ws_size,
                              hipStream_t stream) {
    const float* x      = (const float*)d_in[0];
    const float* y      = (const float*)d_in[1];
    const float* qv_w   = (const float*)d_in[2];
    const float* qv_b   = (const float*)d_in[3];
    const float* k_w    = (const float*)d_in[4];
    const float* k_b    = (const float*)d_in[5];
    const float* rpb    = (const float*)d_in[6];
    const float* proj_w = (const float*)d_in[7];
    const float* proj_b = (const float*)d_in[8];
    const float* n1_w   = (const float*)d_in[9];
    const float* n1_b   = (const float*)d_in[10];
    const float* n2_w   = (const float*)d_in[11];
    const float* n2_b   = (const float*)d_in[12];
    const float* fc1_w  = (const float*)d_in[13];
    const float* fc1_b  = (const float*)d_in[14];
    const float* fc2_w  = (const float*)d_in[15];
    const float* fc2_b  = (const float*)d_in[16];
    float* out = (float*)d_out;

    bf16* qb  = (bf16*)d_ws;                        // later reused as ao (alias)
    bf16* vb  = qb + (size_t)N_PIX * C;
    bf16* kb  = vb + (size_t)N_PIX * C;
    short* wqv  = (short*)(kb + (size_t)N_PIX * C); // 32768
    short* wk   = wqv + 32768;                      // 16384
    short* wproj= wk + 16384;                       // 16384
    short* wfc1 = wproj + 16384;                    // 65536
    short* wfc2 = wfc1 + 65536;                     // 65536  (total ~12.4 MB)
    bf16* ao = qb;                                  // alias: safe (see k_attn)

    k_wconv<<<256, 256, 0, stream>>>(qv_w, k_w, proj_w, fc1_w, fc2_w,
                                     wqv, wk, wproj, wfc1, wfc2);
    k_qkv<<<N_PIX / 32, 256, 0, stream>>>(x, y, wqv, qv_b, wk, k_b, n1_w, n1_b, qb, vb, kb);
    k_attn<<<1024, 256, 0, stream>>>(qb, kb, vb, rpb, ao);
    k_mlp2<<<N_PIX / 32, 256, 0, stream>>>(x, ao, wproj, proj_b, n2_w, n2_b,
                                           wfc1, fc1_b, wfc2, fc2_b, out);
}

// Round 7
// 176.168 us; speedup vs baseline: 10.4266x; 1.0175x over previous
//
#include <hip/hip_runtime.h>
#include <hip/hip_bf16.h>

// CrossNATBlock2D: B=1, H=W=128, C=128, HEADS=4, HD=32, K=7  (fp32 I/O)
// R7: occupancy attack. k_mlp2: 512 thr, LDS 53.0KB -> 3 blocks/CU, x1 bf16,
// proj A-frags from global. k_qkv: 512 thr. k_attn: 4x4 tile (union 100 rows),
// LDS 52.8KB -> 3 blocks/CU, rpb from global.

#define N_PIX 16384
#define C 128
#define HEADS 4
#define HD 32
#define HW 128

typedef __hip_bfloat16 bf16;
typedef __attribute__((ext_vector_type(8))) short bf16x8;
typedef __attribute__((ext_vector_type(4))) float f32x4;

__device__ __forceinline__ float b2f(bf16 v) { return __bfloat162float(v); }
__device__ __forceinline__ short f2bs(float f) {
    bf16 h = __float2bfloat16(f);
    return (short)__bfloat16_as_ushort(h);
}
__device__ __forceinline__ float bs2f(short s) {
    __hip_bfloat16_raw r; r.x = (unsigned short)s;
    return __bfloat162float(__hip_bfloat16(r));
}

// ---------- kernel 0: convert weights fp32 -> bf16 into ws ----------
__global__ __launch_bounds__(256) void k_wconv(
    const float* __restrict__ qv_w, const float* __restrict__ k_w,
    const float* __restrict__ proj_w, const float* __restrict__ fc1_w,
    const float* __restrict__ fc2_w,
    short* __restrict__ wqv, short* __restrict__ wk, short* __restrict__ wproj,
    short* __restrict__ wfc1, short* __restrict__ wfc2) {
    const int i = blockIdx.x * 256 + threadIdx.x;
    if (i < 32768) wqv[i] = f2bs(qv_w[i]);
    if (i < 16384) { wk[i] = f2bs(k_w[i]); wproj[i] = f2bs(proj_w[i]); }
    if (i < 65536) { wfc1[i] = f2bs(fc1_w[i]); wfc2[i] = f2bs(fc2_w[i]); }
}

// ---------- kernel 1: LN1 + QV GEMM + K proj, MFMA, 32 pixels/block, 512 thr ----------
__global__ __launch_bounds__(512, 6) void k_qkv(
    const float* __restrict__ x, const float* __restrict__ y,
    const short* __restrict__ wqv, const float* __restrict__ qv_b,
    const short* __restrict__ wk, const float* __restrict__ k_b,
    const float* __restrict__ n1_w, const float* __restrict__ n1_b,
    bf16* __restrict__ qb, bf16* __restrict__ vb, bf16* __restrict__ kb) {
    __shared__ float xr[32][132];
    __shared__ short xn[32][136];
    __shared__ short yb[32][136];
    __shared__ float redS[32][8], redQ[32][8];
    __shared__ float muA[32], riA[32];
    const int t = threadIdx.x;
    const int pix0 = blockIdx.x * 32;
    for (int e = t; e < 32 * 128; e += 512) {
        const int r = e >> 7, c = e & 127;
        xr[r][c] = x[(pix0 + r) * C + c];
        yb[r][c] = f2bs(y[(pix0 + r) * C + c]);
    }
    __syncthreads();
    if (t < 256) {
        const int r = t >> 3, s = t & 7;
        float sm = 0.f, sq = 0.f;
        for (int i = 0; i < 16; i++) { float v = xr[r][s * 16 + i]; sm += v; sq += v * v; }
        redS[r][s] = sm; redQ[r][s] = sq;
    }
    __syncthreads();
    if (t < 32) {
        float sm = 0.f, sq = 0.f;
        for (int s = 0; s < 8; s++) { sm += redS[t][s]; sq += redQ[t][s]; }
        const float mu = sm * (1.f / 128.f);
        const float var = sq * (1.f / 128.f) - mu * mu;
        muA[t] = mu; riA[t] = rsqrtf(var + 1e-5f);
    }
    __syncthreads();
    for (int e = t; e < 32 * 128; e += 512) {
        const int r = e >> 7, c = e & 127;
        xn[r][c] = f2bs((xr[r][c] - muA[r]) * riA[r] * n1_w[c] + n1_b[c]);
    }
    __syncthreads();
    const int wave = t >> 6, lane = t & 63, quad = lane >> 4, l15 = lane & 15;
    const float scale = 0.1767766952966369f;  // 1/sqrt(32)
    for (int jt = wave; jt < 48; jt += 8) {
        const int mt = jt & 1, nt = jt >> 1;
        f32x4 acc = {0.f, 0.f, 0.f, 0.f};
        if (nt < 16) {  // qv GEMM
            const int n = nt * 16 + l15;
            for (int kt = 0; kt < 4; kt++) {
                bf16x8 a = *(const bf16x8*)&xn[mt * 16 + l15][kt * 32 + quad * 8];
                bf16x8 b = *(const bf16x8*)&wqv[n * C + kt * 32 + quad * 8];
                acc = __builtin_amdgcn_mfma_f32_16x16x32_bf16(a, b, acc, 0, 0, 0);
            }
            const float bias = qv_b[n];
            for (int r = 0; r < 4; r++) {
                const int m = mt * 16 + quad * 4 + r;
                const float v = acc[r] + bias;
                if (n < C) qb[(pix0 + m) * C + n] = __float2bfloat16(v * scale);
                else       vb[(pix0 + m) * C + (n - C)] = __float2bfloat16(v);
            }
        } else {       // k GEMM
            const int n = (nt - 16) * 16 + l15;
            for (int kt = 0; kt < 4; kt++) {
                bf16x8 a = *(const bf16x8*)&yb[mt * 16 + l15][kt * 32 + quad * 8];
                bf16x8 b = *(const bf16x8*)&wk[n * C + kt * 32 + quad * 8];
                acc = __builtin_amdgcn_mfma_f32_16x16x32_bf16(a, b, acc, 0, 0, 0);
            }
            const float bias = k_b[n];
            for (int r = 0; r < 4; r++) {
                const int m = mt * 16 + quad * 4 + r;
                kb[(pix0 + m) * C + n] = __float2bfloat16(acc[r] + bias);
            }
        }
    }
}

// ---------- kernel 2: NATTEN 7x7 MFMA attention, 4x4 pixel tile per block ----------
// union window = 10x10 = 100 neighbors. ao aliases qb (block reads only own q,
// barrier-ordered before writes; disjoint pixels across blocks).
__global__ __launch_bounds__(256) void k_attn(
    const bf16* qb, const bf16* __restrict__ kb,
    const bf16* __restrict__ vb, const float* __restrict__ rpb,
    bf16* ao) {
    __shared__ short KP[100 * 132];   // K during QK^T, then P[4][16] stride 136
    __shared__ short Vl[100 * 132];
    const int t = threadIdx.x;
    const int h = t >> 6, lane = t & 63, quad = lane >> 4, l15 = lane & 15;
    const int i0 = (blockIdx.x >> 5) * 4;      // 32 row-tiles
    const int j0 = (blockIdx.x & 31) * 4;      // 32 col-tiles
    const int rs = min(max(i0 - 3, 0), 118);   // union rows [rs, rs+9]
    const int cs = min(max(j0 - 3, 0), 118);   // union cols [cs, cs+9]
    // stage K and V union windows (100 rows x 128 ch, 16B chunks)
    for (int u = t; u < 100 * 16 * 2; u += 256) {
        const int tv = (u >= 1600) ? 1 : 0;
        const int uu = tv ? u - 1600 : u;
        const int r = uu >> 4, seg = uu & 15;
        const int wr = r / 10, wc = r % 10;
        const size_t g = (size_t)((rs + wr) * HW + cs + wc) * C + seg * 8;
        const uint4 d = *(const uint4*)((tv ? vb : kb) + g);
        *(uint4*)&(tv ? Vl : KP)[r * 132 + seg * 8] = d;
    }
    __syncthreads();
    // ---- QK^T: S[16 pixels][112 (100 valid)], per wave = head ----
    const int pA = (i0 + (l15 >> 2)) * HW + j0 + (l15 & 3);
    const bf16x8 aQ = *(const bf16x8*)(qb + (size_t)pA * C + h * HD + quad * 8);
    f32x4 S[7];
    // per-lane neighbor geometry (hoisted out of r-loop)
    int aiL[7], ajL[7]; bool inb[7];
    for (int nt = 0; nt < 7; nt++) {
        const int nb = nt * 16 + l15;
        aiL[nt] = rs + nb / 10;
        ajL[nt] = cs + nb % 10;
        inb[nt] = nb < 100;
        const bf16x8 bK = *(const bf16x8*)&KP[(nt * 16 + l15) * 132 + h * HD + quad * 8];
        f32x4 z = {0.f, 0.f, 0.f, 0.f};
        S[nt] = __builtin_amdgcn_mfma_f32_16x16x32_bf16(aQ, bK, z, 0, 0, 0);
    }
    // ---- bias + validity mask + softmax (C-layout: row=quad*4+r, col=nt*16+l15) ----
    const float* rpbh = rpb + h * 169;
    float sm[4];
    for (int r = 0; r < 4; r++) {
        const int m = quad * 4 + r;
        const int i = i0 + (m >> 2), j = j0 + (m & 3);
        const int shi = min(max(i - 3, 0), 121);
        const int swj = min(max(j - 3, 0), 121);
        float best = -1e30f;
        for (int nt = 0; nt < 7; nt++) {
            const int ai = aiL[nt], aj = ajL[nt];
            const bool valid = inb[nt] & (ai >= shi) & (ai <= shi + 6) & (aj >= swj) & (aj <= swj + 6);
            const int ri = min(max(ai - i + 6, 0), 12);
            const int rj = min(max(aj - j + 6, 0), 12);
            const float v = valid ? (S[nt][r] + rpbh[ri * 13 + rj]) : -1e30f;
            S[nt][r] = v;
            best = fmaxf(best, v);
        }
        for (int msk = 1; msk < 16; msk <<= 1) best = fmaxf(best, __shfl_xor(best, msk, 64));
        float s = 0.f;
        for (int nt = 0; nt < 7; nt++) {
            const float e = __expf(S[nt][r] - best);
            S[nt][r] = e;
            s += e;
        }
        for (int msk = 1; msk < 16; msk <<= 1) s += __shfl_xor(s, msk, 64);
        sm[r] = 1.f / s;
    }
    __syncthreads();   // all waves done reading KP as K
    // ---- write P (bf16) over KP: row stride 136, zero pad cols 112..127 ----
    for (int r = 0; r < 4; r++) {
        short* prow = &KP[(h * 16 + quad * 4 + r) * 136];
        for (int nt = 0; nt < 7; nt++)
            prow[nt * 16 + l15] = f2bs(S[nt][r] * sm[r]);
        prow[112 + l15] = 0;
    }
    __syncthreads();
    // ---- PV: out[16][32] per head ----
    f32x4 O0 = {0.f, 0.f, 0.f, 0.f}, O1 = {0.f, 0.f, 0.f, 0.f};
    for (int kt = 0; kt < 4; kt++) {
        const bf16x8 aP = *(const bf16x8*)&KP[(h * 16 + l15) * 136 + kt * 32 + quad * 8];
        for (int nt2 = 0; nt2 < 2; nt2++) {
            bf16x8 bV;
            const int ch = h * HD + nt2 * 16 + l15;
#pragma unroll
            for (int jj = 0; jj < 8; jj++) {
                const int nbr = kt * 32 + quad * 8 + jj;
                bV[jj] = (nbr < 100) ? Vl[nbr * 132 + ch] : (short)0;
            }
            if (nt2 == 0) O0 = __builtin_amdgcn_mfma_f32_16x16x32_bf16(aP, bV, O0, 0, 0, 0);
            else          O1 = __builtin_amdgcn_mfma_f32_16x16x32_bf16(aP, bV, O1, 0, 0, 0);
        }
    }
    for (int r = 0; r < 4; r++) {
        const int m = quad * 4 + r;
        const int p = (i0 + (m >> 2)) * HW + j0 + (m & 3);
        ao[(size_t)p * C + h * HD + l15] = __float2bfloat16(O0[r]);
        ao[(size_t)p * C + h * HD + 16 + l15] = __float2bfloat16(O1[r]);
    }
}

// ---------- kernel 3: proj + residual + LN2 + FC1 + GELU + FC2 + residual ----------
// 512 threads, x1 kept bf16 in LDS (R3-proven), proj A-frags from global ao.
__global__ __launch_bounds__(512, 6) void k_mlp2(
    const float* __restrict__ x, const bf16* __restrict__ ao,
    const short* __restrict__ wproj, const float* __restrict__ proj_b,
    const float* __restrict__ n2_w, const float* __restrict__ n2_b,
    const short* __restrict__ wfc1, const float* __restrict__ fc1_b,
    const short* __restrict__ wfc2, const float* __restrict__ fc2_b,
    float* __restrict__ out) {
    __shared__ short x1b[32][136];
    __shared__ short xn[32][136];
    __shared__ short hb[32][520];
    __shared__ float redS[32][8], redQ[32][8];
    __shared__ float muA[32], riA[32];
    const int t = threadIdx.x;
    const int pix0 = blockIdx.x * 32;
    const int wave = t >> 6, lane = t & 63, quad = lane >> 4, l15 = lane & 15;
    // proj MFMA: x1 = x + ao @ wproj^T + proj_b -> x1b (bf16)
    for (int jt = wave; jt < 16; jt += 8) {
        const int mt = jt >> 3, nt = jt & 7;
        const int n = nt * 16 + l15;
        const bf16* aop = ao + (size_t)(pix0 + mt * 16 + l15) * C;
        f32x4 acc = {0.f, 0.f, 0.f, 0.f};
        for (int kt = 0; kt < 4; kt++) {
            bf16x8 a = *(const bf16x8*)(aop + kt * 32 + quad * 8);
            bf16x8 b = *(const bf16x8*)&wproj[n * C + kt * 32 + quad * 8];
            acc = __builtin_amdgcn_mfma_f32_16x16x32_bf16(a, b, acc, 0, 0, 0);
        }
        const float bias = proj_b[n];
        for (int r = 0; r < 4; r++) {
            const int m = mt * 16 + quad * 4 + r;
            x1b[m][n] = f2bs(x[(pix0 + m) * C + n] + acc[r] + bias);
        }
    }
    __syncthreads();
    if (t < 256) {
        const int r = t >> 3, s = t & 7;
        float sm = 0.f, sq = 0.f;
        for (int i = 0; i < 16; i++) { float v = bs2f(x1b[r][s * 16 + i]); sm += v; sq += v * v; }
        redS[r][s] = sm; redQ[r][s] = sq;
    }
    __syncthreads();
    if (t < 32) {
        float sm = 0.f, sq = 0.f;
        for (int s = 0; s < 8; s++) { sm += redS[t][s]; sq += redQ[t][s]; }
        const float mu = sm * (1.f / 128.f);
        const float var = sq * (1.f / 128.f) - mu * mu;
        muA[t] = mu; riA[t] = rsqrtf(var + 1e-5f);
    }
    __syncthreads();
    for (int e = t; e < 32 * 128; e += 512) {
        const int r = e >> 7, c = e & 127;
        xn[r][c] = f2bs((bs2f(x1b[r][c]) - muA[r]) * riA[r] * n2_w[c] + n2_b[c]);
    }
    __syncthreads();
    // fc1 + gelu
    for (int jt = wave; jt < 64; jt += 8) {
        const int mt = jt >> 5, nt = jt & 31;
        const int n = nt * 16 + l15;
        f32x4 acc = {0.f, 0.f, 0.f, 0.f};
        for (int kt = 0; kt < 4; kt++) {
            bf16x8 a = *(const bf16x8*)&xn[mt * 16 + l15][kt * 32 + quad * 8];
            bf16x8 b = *(const bf16x8*)&wfc1[n * C + kt * 32 + quad * 8];
            acc = __builtin_amdgcn_mfma_f32_16x16x32_bf16(a, b, acc, 0, 0, 0);
        }
        const float bias = fc1_b[n];
        for (int r = 0; r < 4; r++) {
            const int m = mt * 16 + quad * 4 + r;
            float v = acc[r] + bias;
            v = 0.5f * v * (1.f + erff(v * 0.70710678118654752f));
            hb[m][n] = f2bs(v);
        }
    }
    __syncthreads();
    // fc2 + residual -> out
    for (int jt = wave; jt < 16; jt += 8) {
        const int mt = jt >> 3, nt = jt & 7;
        const int n = nt * 16 + l15;
        f32x4 acc = {0.f, 0.f, 0.f, 0.f};
        for (int kt = 0; kt < 16; kt++) {
            bf16x8 a = *(const bf16x8*)&hb[mt * 16 + l15][kt * 32 + quad * 8];
            bf16x8 b = *(const bf16x8*)&wfc2[n * 512 + kt * 32 + quad * 8];
            acc = __builtin_amdgcn_mfma_f32_16x16x32_bf16(a, b, acc, 0, 0, 0);
        }
        const float bias = fc2_b[n];
        for (int r = 0; r < 4; r++) {
            const int m = mt * 16 + quad * 4 + r;
            out[(pix0 + m) * C + n] = acc[r] + bias + bs2f(x1b[m][n]);
        }
    }
}

extern "C" void kernel_launch(void* const* d_in, const int* in_sizes, int n_in,
                              void* d_out, int out_size, void* d_ws, size_t ws_size,
                              hipStream_t stream) {
    const float* x      = (const float*)d_in[0];
    const float* y      = (const float*)d_in[1];
    const float* qv_w   = (const float*)d_in[2];
    const float* qv_b   = (const float*)d_in[3];
    const float* k_w    = (const float*)d_in[4];
    const float* k_b    = (const float*)d_in[5];
    const float* rpb    = (const float*)d_in[6];
    const float* proj_w = (const float*)d_in[7];
    const float* proj_b = (const float*)d_in[8];
    const float* n1_w   = (const float*)d_in[9];
    const float* n1_b   = (const float*)d_in[10];
    const float* n2_w   = (const float*)d_in[11];
    const float* n2_b   = (const float*)d_in[12];
    const float* fc1_w  = (const float*)d_in[13];
    const float* fc1_b  = (const float*)d_in[14];
    const float* fc2_w  = (const float*)d_in[15];
    const float* fc2_b  = (const float*)d_in[16];
    float* out = (float*)d_out;

    bf16* qb  = (bf16*)d_ws;                        // later reused as ao (alias)
    bf16* vb  = qb + (size_t)N_PIX * C;
    bf16* kb  = vb + (size_t)N_PIX * C;
    short* wqv  = (short*)(kb + (size_t)N_PIX * C); // 32768
    short* wk   = wqv + 32768;                      // 16384
    short* wproj= wk + 16384;                       // 16384
    short* wfc1 = wproj + 16384;                    // 65536
    short* wfc2 = wfc1 + 65536;                     // 65536  (total ~12.4 MB)
    bf16* ao = qb;                                  // alias: safe (see k_attn)

    k_wconv<<<256, 256, 0, stream>>>(qv_w, k_w, proj_w, fc1_w, fc2_w,
                                     wqv, wk, wproj, wfc1, wfc2);
    k_qkv<<<N_PIX / 32, 512, 0, stream>>>(x, y, wqv, qv_b, wk, k_b, n1_w, n1_b, qb, vb, kb);
    k_attn<<<1024, 256, 0, stream>>>(qb, kb, vb, rpb, ao);
    k_mlp2<<<N_PIX / 32, 512, 0, stream>>>(x, ao, wproj, proj_b, n2_w, n2_b,
                                           wfc1, fc1_b, wfc2, fc2_b, out);
}